// Round 7
// baseline (336.606 us; speedup 1.0000x reference)
//
#include <hip/hip_runtime.h>
#include <math.h>

// x = (16, 32, 65536) fp32. One block per row; row streamed through LDS in
// 16 chunks of 4096. Three scans (two data-dependent row thresholds):
//   S1: stats1 over residual(x)
//   S2: stats2 over residual(y), y=apply1(x) materialized per-chunk in LDS
//   S3: out = apply2(y, th2),    y re-materialized per-chunk in LDS
// y never touches HBM -> floor 134 R + 134 W. Round-6 lessons applied:
//  - all LDS access b128: XOR swizzle at float4 granularity (alignment-
//    preserving, conflict-free for stride-1 and stride-2 lane patterns)
//  - y computed ONCE per element per scan (was 3.75x redundant)
// fmaf chain order / f64 stats order identical to the passing round-6 kernel.
#define LROW   65536
#define NROWS  512
#define NT     512              // 8 waves
#define NW     (NT / 64)
#define NCHK   16
#define CHUNK  4096
#define EPC    8                // elements per thread per chunk
#define HBX    12               // x halo (staged), multiple of 4
#define HBY    8                // y halo offset in LDS, multiple of 4
#define NFXP   1032             // padded float4 count for x buffers
#define NFYP   1032             // padded float4 count for y buffer

#define TREND_SCALING       0.6f
#define DETAIL_PRESERVATION 0.85f
#define SPIKE_THRESHOLD     3.5f
#define SPIKE_DAMPING       0.35f
#define EPSV                1e-6f

// float4-granularity XOR swizzle: preserves 16B alignment; spreads both
// stride-1 (staging) and stride-2 (window-read) lane patterns across all
// 8 bank-groups.
__device__ __forceinline__ int swz(int I) { return I ^ ((I >> 3) & 7); }

__device__ __forceinline__ float ldsGet(const float4* B, int i) {
    return ((const float*)&B[swz(i >> 2)])[i & 3];
}
__device__ __forceinline__ void ldsPut(float4* B, int i, float v) {
    ((float*)&B[swz(i >> 2)])[i & 3] = v;
}

// Deterministic block threshold from per-thread f64 partials.
__device__ __forceinline__ float block_thresh(double s, double q,
                                              double* __restrict__ wred,
                                              const int tid) {
#pragma unroll
    for (int off = 32; off > 0; off >>= 1) {
        s += __shfl_xor(s, off);
        q += __shfl_xor(q, off);
    }
    if ((tid & 63) == 0) {
        wred[tid >> 6] = s;
        wred[(tid >> 6) + NW] = q;
    }
    __syncthreads();
    double S = 0.0, Q = 0.0;
#pragma unroll
    for (int w = 0; w < NW; w++) { S += wred[w]; Q += wred[w + NW]; }
    const double N = (double)LROW;
    double var = (Q - S * S / N) / (N - 1.0);
    if (var < 0.0) var = 0.0;
    return fmaxf((float)sqrt(var), EPSV) * SPIKE_THRESHOLD;
}

// one iteration-1 output value from an x-window (xa[j] = x[p-5+j])
__device__ __forceinline__ float y_of(const float* xa, float w5, float w11,
                                      float th1) {
    float lac = 0.f, tac = 0.f;
#pragma unroll
    for (int d = 0; d < 5; d++) lac = fmaf(xa[3 + d], w5, lac);
#pragma unroll
    for (int d = 0; d < 11; d++) tac = fmaf(xa[d], w11, tac);
    float cur = xa[5];
    float r = cur - lac;
    r = (fabsf(r) > th1) ? r * SPIKE_DAMPING : r;
    float comb = (1.0f - TREND_SCALING) * lac + TREND_SCALING * tac;
    return comb + DETAIL_PRESERVATION * r;
}

// ---------------------------------------------------------------------------
__global__ __launch_bounds__(NT) void k_fused(const float* __restrict__ x,
                                              float* __restrict__ out,
                                              const float* __restrict__ k5,
                                              const float* __restrict__ k11) {
    __shared__ float4 bx[2][NFXP];   // double-buffered x chunk (+/-12 halo)
    __shared__ float4 by[NFYP];      // y chunk (+/-5 used, offset 8)
    __shared__ double wred[2 * NW];

    const int row = blockIdx.x;
    const int t = threadIdx.x;
    const size_t rowBase = (size_t)row * LROW;
    const float w5 = k5[0];
    const float w11 = k11[0];
    const int E0 = t * EPC;
    const float4* X4 = (const float4*)(x + rowBase);

    float4 r0, r1;
    float hreg;

#define LOADC(c)                                                              \
    {                                                                         \
        r0 = X4[(c) * 1024 + t];                                              \
        r1 = X4[(c) * 1024 + t + NT];                                         \
        if (t < 2 * HBX) {                                                    \
            int i = (t < HBX) ? t : CHUNK + t;                                \
            int g = (c) * CHUNK + i - HBX;                                    \
            g = (g < 0) ? -g : (g >= LROW ? 2 * LROW - 2 - g : g);            \
            hreg = x[rowBase + g];                                            \
        }                                                                     \
    }
#define STOREC(B)                                                             \
    {                                                                         \
        (B)[swz(t + 3)] = r0;                                                 \
        (B)[swz(t + NT + 3)] = r1;                                            \
        if (t < 2 * HBX) {                                                    \
            int i = (t < HBX) ? t : CHUNK + t;                                \
            ldsPut((B), i, hreg);                                             \
        }                                                                     \
    }
// compute this thread's 8 y values + edge-halo y, store into by.
// xw[m] = x[E0-8+m] (24 floats from 6 b128 at f4 base 2t+1).
#define MAKE_Y(B, th1v)                                                       \
    {                                                                         \
        float xw[24];                                                         \
        _Pragma("unroll") for (int j = 0; j < 6; ++j) {                       \
            float4 wv = (B)[swz(2 * t + 1 + j)];                              \
            xw[4 * j] = wv.x; xw[4 * j + 1] = wv.y;                           \
            xw[4 * j + 2] = wv.z; xw[4 * j + 3] = wv.w;                       \
        }                                                                     \
        float yo[EPC];                                                        \
        _Pragma("unroll") for (int k = 0; k < EPC; ++k)                       \
            yo[k] = y_of(&xw[k + 3], w5, w11, (th1v));                        \
        by[swz(2 * t + 2)] = make_float4(yo[0], yo[1], yo[2], yo[3]);         \
        by[swz(2 * t + 3)] = make_float4(yo[4], yo[5], yo[6], yo[7]);         \
        if (t < 10) {                                                         \
            int p = (t < 5) ? (t - 5) : (CHUNK + t - 5);                      \
            float xa[11];                                                     \
            _Pragma("unroll") for (int j = 0; j < 11; ++j)                    \
                xa[j] = ldsGet((B), p - 5 + j + HBX);                         \
            ldsPut(by, p + HBY, y_of(xa, w5, w11, (th1v)));                   \
        }                                                                     \
    }

    // ================= S1: stats over residual(x) =================
    double s = 0.0, q = 0.0;
    LOADC(0)
#pragma unroll 1
    for (int c = 0; c < NCHK; ++c) {
        float4* B = bx[c & 1];
        STOREC(B)
        if (c + 1 < NCHK) LOADC(c + 1)
        __syncthreads();
        float v[16];  // v[m] = x[E0-4+m]
#pragma unroll
        for (int j = 0; j < 4; ++j) {
            float4 wv = B[swz(2 * t + 2 + j)];
            v[4 * j] = wv.x; v[4 * j + 1] = wv.y;
            v[4 * j + 2] = wv.z; v[4 * j + 3] = wv.w;
        }
#pragma unroll
        for (int k = 0; k < EPC; ++k) {
            float lac = 0.f;
#pragma unroll
            for (int d = 0; d < 5; ++d) lac = fmaf(v[k + 2 + d], w5, lac);
            float r = v[k + 4] - lac;
            s += (double)r;
            q += (double)r * (double)r;
        }
    }
    const float th1 = block_thresh(s, q, wred, t);

    // ============ S2: stats over residual(y), y materialized ============
    s = 0.0; q = 0.0;
    LOADC(0)
#pragma unroll 1
    for (int c = 0; c < NCHK; ++c) {
        float4* B = bx[c & 1];
        STOREC(B)
        if (c + 1 < NCHK) LOADC(c + 1)
        __syncthreads();
        MAKE_Y(B, th1)
        __syncthreads();
        float yw[16];  // yw[m] = y[E0-4+m]
#pragma unroll
        for (int j = 0; j < 4; ++j) {
            float4 wv = by[swz(2 * t + 1 + j)];
            yw[4 * j] = wv.x; yw[4 * j + 1] = wv.y;
            yw[4 * j + 2] = wv.z; yw[4 * j + 3] = wv.w;
        }
#pragma unroll
        for (int k = 0; k < EPC; ++k) {
            float lac = 0.f;
#pragma unroll
            for (int d = 0; d < 5; ++d) lac = fmaf(yw[k + 2 + d], w5, lac);
            float r = yw[k + 4] - lac;
            s += (double)r;
            q += (double)r * (double)r;
        }
    }
    const float th2 = block_thresh(s, q, wred, t);

    // ================= S3: out = apply2(y, th2) =================
    LOADC(0)
#pragma unroll 1
    for (int c = 0; c < NCHK; ++c) {
        float4* B = bx[c & 1];
        STOREC(B)
        if (c + 1 < NCHK) LOADC(c + 1)
        __syncthreads();
        MAKE_Y(B, th1)
        __syncthreads();
        float yw[24];  // yw[m] = y[E0-8+m]
#pragma unroll
        for (int j = 0; j < 6; ++j) {
            float4 wv = by[swz(2 * t + j)];
            yw[4 * j] = wv.x; yw[4 * j + 1] = wv.y;
            yw[4 * j + 2] = wv.z; yw[4 * j + 3] = wv.w;
        }
        float o[EPC];
#pragma unroll
        for (int k = 0; k < EPC; ++k) {
            float lac = 0.f, tac = 0.f;
#pragma unroll
            for (int d = 0; d < 5; ++d) lac = fmaf(yw[k + 6 + d], w5, lac);
#pragma unroll
            for (int d = 0; d < 11; ++d) tac = fmaf(yw[k + 3 + d], w11, tac);
            float cur = yw[k + 8];
            float r = cur - lac;
            r = (fabsf(r) > th2) ? r * SPIKE_DAMPING : r;
            float comb = (1.0f - TREND_SCALING) * lac + TREND_SCALING * tac;
            o[k] = comb + DETAIL_PRESERVATION * r;
        }
        float4* O4 = (float4*)(out + rowBase + c * CHUNK + E0);
        O4[0] = make_float4(o[0], o[1], o[2], o[3]);
        O4[1] = make_float4(o[4], o[5], o[6], o[7]);
    }
#undef LOADC
#undef STOREC
#undef MAKE_Y
}

extern "C" void kernel_launch(void* const* d_in, const int* in_sizes, int n_in,
                              void* d_out, int out_size, void* d_ws, size_t ws_size,
                              hipStream_t stream) {
    (void)in_sizes; (void)n_in; (void)out_size; (void)d_ws; (void)ws_size;
    const float* x = (const float*)d_in[0];
    const float* k5 = (const float*)d_in[1];
    const float* k11 = (const float*)d_in[2];
    float* out = (float*)d_out;

    hipLaunchKernelGGL(k_fused, dim3(NROWS), dim3(NT), 0, stream, x, out, k5, k11);
}

// Round 8
// 327.078 us; speedup vs baseline: 1.0291x; 1.0291x over previous
//
#include <hip/hip_runtime.h>
#include <math.h>

// x = (16, 32, 65536) fp32. One block per row, 8 waves; each wave autonomously
// processes a contiguous 8192-element segment in 16 sub-steps of 512
// (8 elems/lane). NO LDS data staging, NO per-chunk barriers (rounds 6/7:
// 96 serialized barriers + LDS pipe + 1.5-2e7 conflict cycles pinned us at
// ~180us with VALUBusy ~50%). Every lane loads its own overlapping window
// straight from global (L1/L2-served; adjacent lanes share lines).
// Only 2 barriers total (the two row-threshold reductions).
//
// Numerics policy (flip-safety): the spike compare |r|>th is discontinuous.
// Chains feeding a compare keep the exact 5-fmaf form of all prior passing
// kernels (lac in S2/S3 y-eval, lac-on-y in S3 final). Box filters feeding
// only linear paths or f64 statistics use per-sub-step re-anchored sliding
// sums (err ~1e-7 -> th err ~1e-9, no flip risk):
//   S1 box5(x) (stats only), all box11 tac (linear), S2 box5(y) (stats only).
// Stats: f32 within an 8-elem sub-step, promoted to f64 per sub-step,
// 64-lane f64 butterfly + 8 wave partials finalized in fixed order.
#define LROW   65536
#define NROWS  512
#define NT     512
#define NWAVE  8
#define WSEG   (LROW / NWAVE)     // 8192 elems per wave segment
#define NSUB   16
#define SUBW   (WSEG / NSUB)      // 512 elems per wave per sub-step
#define EPL    8                  // elems per lane per sub-step

#define TREND_SCALING       0.6f
#define DETAIL_PRESERVATION 0.85f
#define SPIKE_THRESHOLD     3.5f
#define SPIKE_DAMPING       0.35f
#define EPSV                1e-6f

__device__ __forceinline__ int refl(int g) {
    g = (g < 0) ? -g : g;
    return (g >= LROW) ? (2 * LROW - 2 - g) : g;
}

// Load 4*N4 floats starting at row-index W0 (16B-aligned). Interior lanes:
// N4 float4 loads. Row-edge lanes (<=2 per edge wave): scalar reflected path.
template <int N4>
__device__ __forceinline__ void loadwin(const float* __restrict__ xr, int W0,
                                        float* v) {
    if (W0 >= 0 && W0 + 4 * N4 <= LROW) {
        const float4* b = (const float4*)(xr + W0);
#pragma unroll
        for (int m = 0; m < N4; ++m) {
            float4 t = b[m];
            v[4 * m + 0] = t.x; v[4 * m + 1] = t.y;
            v[4 * m + 2] = t.z; v[4 * m + 3] = t.w;
        }
    } else {
#pragma unroll
        for (int m = 0; m < 4 * N4; ++m) v[m] = xr[refl(W0 + m)];
    }
}

// Deterministic row threshold: f64 butterfly + NWAVE partials, fixed-order
// finalize replicated by every thread. One barrier; caller provides a
// dedicated buffer so back-to-back calls need no extra barrier.
__device__ __forceinline__ float block_thresh(double s, double q,
                                              double* __restrict__ wred,
                                              const int tid) {
#pragma unroll
    for (int off = 32; off > 0; off >>= 1) {
        s += __shfl_xor(s, off);
        q += __shfl_xor(q, off);
    }
    if ((tid & 63) == 0) {
        wred[tid >> 6] = s;
        wred[(tid >> 6) + NWAVE] = q;
    }
    __syncthreads();
    double S = 0.0, Q = 0.0;
#pragma unroll
    for (int w = 0; w < NWAVE; w++) { S += wred[w]; Q += wred[w + NWAVE]; }
    const double N = (double)LROW;
    double var = (Q - S * S / N) / (N - 1.0);
    if (var < 0.0) var = 0.0;
    return fmaxf((float)sqrt(var), EPSV) * SPIKE_THRESHOLD;
}

// ---------------------------------------------------------------------------
__global__ __launch_bounds__(NT, 2) void k_fused(const float* __restrict__ x,
                                                 float* __restrict__ out,
                                                 const float* __restrict__ k5,
                                                 const float* __restrict__ k11) {
    __shared__ double wredA[2 * NWAVE];
    __shared__ double wredB[2 * NWAVE];

    const int row = blockIdx.x;
    const int tid = threadIdx.x;
    const int wv = tid >> 6;
    const int ln = tid & 63;
    const float* xr = x + (size_t)row * LROW;
    float* outr = out + (size_t)row * LROW;
    const float w5 = k5[0];
    const float w11 = k11[0];
    const int base0 = wv * WSEG + ln * EPL;

    // ================= S1: stats over residual(x) =================
    double s = 0.0, q = 0.0;
#pragma unroll 1
    for (int j = 0; j < NSUB; ++j) {
        const int p = base0 + j * SUBW;
        float v[16];                      // v[m] = x[p-4+m]
        loadwin<4>(xr, p - 4, v);
        float bs = v[2] + v[3] + v[4] + v[5] + v[6];   // box5 sum at k=0
        float sf = 0.f, qf = 0.f;
#pragma unroll
        for (int k = 0; k < EPL; ++k) {
            if (k) bs += v[k + 6] - v[k + 1];
            float r = v[k + 4] - bs * w5;
            sf += r;
            qf = fmaf(r, r, qf);
        }
        s += (double)sf;
        q += (double)qf;
    }
    const float th1 = block_thresh(s, q, wredA, tid);

    // ========== S2: stats over residual(y), y recomputed locally ==========
    s = 0.0; q = 0.0;
#pragma unroll 1
    for (int j = 0; j < NSUB; ++j) {
        const int p = base0 + j * SUBW;
        float v[24];                      // v[m] = x[p-8+m]
        loadwin<6>(xr, p - 8, v);
        // y at positions p-2 .. p+9  (i = 0..11, pos = p-2+i)
        float ts = v[1] + v[2] + v[3] + v[4] + v[5] + v[6] + v[7] + v[8] +
                   v[9] + v[10] + v[11];  // box11 sum at i=0
        float yv[12];
#pragma unroll
        for (int i = 0; i < 12; ++i) {
            if (i) ts += v[i + 11] - v[i];
            float lac = 0.f;              // EXACT chain (feeds compare)
#pragma unroll
            for (int d = 0; d < 5; ++d) lac = fmaf(v[i + 4 + d], w5, lac);
            float cur = v[i + 6];
            float r = cur - lac;
            r = (fabsf(r) > th1) ? r * SPIKE_DAMPING : r;
            float comb = (1.0f - TREND_SCALING) * lac +
                         TREND_SCALING * (ts * w11);
            yv[i] = comb + DETAIL_PRESERVATION * r;
        }
        // residual(y) at p..p+7 (stats only -> sliding box5 on y)
        float b5 = yv[0] + yv[1] + yv[2] + yv[3] + yv[4];
        float sf = 0.f, qf = 0.f;
#pragma unroll
        for (int k = 0; k < EPL; ++k) {
            if (k) b5 += yv[k + 4] - yv[k - 1];
            float r2 = yv[k + 2] - b5 * w5;
            sf += r2;
            qf = fmaf(r2, r2, qf);
        }
        s += (double)sf;
        q += (double)qf;
    }
    const float th2 = block_thresh(s, q, wredB, tid);

    // ================= S3: out = apply2(y(x), th2) =================
#pragma unroll 1
    for (int j = 0; j < NSUB; ++j) {
        const int p = base0 + j * SUBW;
        float v[32];                      // v[m] = x[p-12+m]
        loadwin<8>(xr, p - 12, v);
        // y at positions p-5 .. p+12  (i = 0..17, pos = p-5+i)
        float ts = v[2] + v[3] + v[4] + v[5] + v[6] + v[7] + v[8] + v[9] +
                   v[10] + v[11] + v[12];
        float yv[18];
#pragma unroll
        for (int i = 0; i < 18; ++i) {
            if (i) ts += v[i + 12] - v[i + 1];
            float lac = 0.f;              // EXACT chain (feeds compare)
#pragma unroll
            for (int d = 0; d < 5; ++d) lac = fmaf(v[i + 5 + d], w5, lac);
            float cur = v[i + 7];
            float r = cur - lac;
            r = (fabsf(r) > th1) ? r * SPIKE_DAMPING : r;
            float comb = (1.0f - TREND_SCALING) * lac +
                         TREND_SCALING * (ts * w11);
            yv[i] = comb + DETAIL_PRESERVATION * r;
        }
        // out at p..p+7 (k = 0..7): lac2 exact (feeds compare), tac2 sliding
        float t2 = yv[0] + yv[1] + yv[2] + yv[3] + yv[4] + yv[5] + yv[6] +
                   yv[7] + yv[8] + yv[9] + yv[10];
        float o[EPL];
#pragma unroll
        for (int k = 0; k < EPL; ++k) {
            if (k) t2 += yv[k + 10] - yv[k - 1];
            float lac2 = 0.f;
#pragma unroll
            for (int d = 0; d < 5; ++d) lac2 = fmaf(yv[k + 3 + d], w5, lac2);
            float cur2 = yv[k + 5];
            float r2 = cur2 - lac2;
            r2 = (fabsf(r2) > th2) ? r2 * SPIKE_DAMPING : r2;
            float comb2 = (1.0f - TREND_SCALING) * lac2 +
                          TREND_SCALING * (t2 * w11);
            o[k] = comb2 + DETAIL_PRESERVATION * r2;
        }
        float4* o4 = (float4*)(outr + p);
        o4[0] = make_float4(o[0], o[1], o[2], o[3]);
        o4[1] = make_float4(o[4], o[5], o[6], o[7]);
    }
}

extern "C" void kernel_launch(void* const* d_in, const int* in_sizes, int n_in,
                              void* d_out, int out_size, void* d_ws, size_t ws_size,
                              hipStream_t stream) {
    (void)in_sizes; (void)n_in; (void)out_size; (void)d_ws; (void)ws_size;
    const float* x = (const float*)d_in[0];
    const float* k5 = (const float*)d_in[1];
    const float* k11 = (const float*)d_in[2];
    float* out = (float*)d_out;

    hipLaunchKernelGGL(k_fused, dim3(NROWS), dim3(NT), 0, stream, x, out, k5, k11);
}